// Round 1
// 479.940 us; speedup vs baseline: 1.0044x; 1.0044x over previous
//
#include <hip/hip_runtime.h>

#define NA 8192   // atoms
#define NB 8192   // bonds

// ---------- pack x[N,3] -> float4[N] (xyz + sq) in workspace ----------
// sq must replicate numpy's np.sum(x*x, axis=1) rounding: plain RN mults,
// sequential adds ((x^2 + y^2) + z^2). __f*_rn blocks fp-contract fusion.
__global__ void pack_x_kernel(const float* __restrict__ x, float4* __restrict__ x4, int n) {
    int t = blockIdx.x * blockDim.x + threadIdx.x;
    if (t < n) {
        float a = x[3 * t + 0], b = x[3 * t + 1], c = x[3 * t + 2];
        float sq = __fadd_rn(__fadd_rn(__fmul_rn(a, a), __fmul_rn(b, b)), __fmul_rn(c, c));
        x4[t] = make_float4(a, b, c, sq);
    }
}

// ---------- reduction helper: wave shuffle -> LDS -> one atomic ----------
__device__ __forceinline__ void block_reduce_atomic(float v, float* __restrict__ out) {
#pragma unroll
    for (int off = 32; off > 0; off >>= 1) v += __shfl_down(v, off);
    __shared__ float smem[8];
    const int lane = threadIdx.x & 63;
    const int wave = threadIdx.x >> 6;
    if (lane == 0) smem[wave] = v;
    __syncthreads();
    if (threadIdx.x == 0) {
        float s = 0.0f;
        const int nw = (int)(blockDim.x >> 6);
        for (int w = 0; w < nw; ++w) s += smem[w];
        atomicAdd(out, s);
    }
}

// ---------- bond term (magnitude ~1e9; simple) ----------
__global__ void bond_kernel(const float* __restrict__ x, const int* __restrict__ pairs,
                            const float* __restrict__ kb, const float* __restrict__ b0,
                            float* __restrict__ out) {
    int t = blockIdx.x * blockDim.x + threadIdx.x;
    float v = 0.0f;
    if (t < NB) {
        int i = pairs[2 * t + 0] & (NA - 1);
        int j = pairs[2 * t + 1] & (NA - 1);
        float dx = __fsub_rn(x[3 * i + 0], x[3 * j + 0]);
        float dy = __fsub_rn(x[3 * i + 1], x[3 * j + 1]);
        float dz = __fsub_rn(x[3 * i + 2], x[3 * j + 2]);
        float ss = __fadd_rn(__fadd_rn(__fmul_rn(dx, dx), __fmul_rn(dy, dy)), __fmul_rn(dz, dz));
        float dis = __fsqrt_rn(ss);
        float d = __fsub_rn(dis, b0[t]);
        v = __fmul_rn(kb[t], __fmul_rn(d, d));
    }
    block_reduce_atomic(v, out);
}

// ---------- LJ pair energy, replicating the reference's Gram-form rounding ----
// ref: d2 = sq_i + sq_j - 2*dot(xi,xj)   (fp32, catastrophic cancellation we
// must REPRODUCE, not fix); dot per BLAS k-ordered FMA accumulation;
// dist = sqrt_rn(d2); rod = rmin/dist (correctly rounded).
// DO NOT CHANGE the operation sequence here — bit-compat with reference.
__device__ __forceinline__ float lj_pair(const float4 xi, const float4 xj,
                                         const float e, const float rm) {
    float dot = fmaf(xi.z, xj.z, fmaf(xi.y, xj.y, __fmul_rn(xi.x, xj.x)));
    float t   = __fadd_rn(xi.w, xj.w);          // sq_i + sq_j
    float d2  = fmaf(-2.0f, dot, t);            // == RN(t - 2*dot), 2*dot exact
    d2 = fmaxf(d2, 0.0f);
    float dist = (d2 > 0.0f) ? __fsqrt_rn(d2) : 0.0f;
    float rod  = __fdiv_rn(rm, dist);
    float r2 = __fmul_rn(rod, rod);
    float r6 = __fmul_rn(__fmul_rn(r2, r2), r2);
    return __fmul_rn(e, __fsub_rn(__fmul_rn(r6, r6), __fmul_rn(2.0f, r6)));
}

// ---------- all-pairs LJ, strict upper triangle ----------
// grid = NA/2 blocks; block b handles rows b and NA-1-b => exactly NA-1 pairs/block.
// Mapping: one j per lane (j = i+1+tid, stride blockDim) so x4[j], eps[j],
// rmin[j] are all unit-stride coalesced across the wave. The previous
// float4-of-eps mapping made the four x4 loads 64B-lane-stride gathers
// (4 KB spread per wave request) — TCP/L1-sector-bound, ~3x off HBM roofline.
// 4x unroll (stride-256 apart) keeps 12 loads in flight per thread.
__global__ __launch_bounds__(256) void lj_kernel(const float4* __restrict__ x4,
                                                 const float* __restrict__ eps,
                                                 const float* __restrict__ rmin,
                                                 float* __restrict__ out) {
    const int N = NA;
    float acc = 0.0f;
    const int rowA = (int)blockIdx.x;
    const int rowB = N - 1 - rowA;

#pragma unroll
    for (int r = 0; r < 2; ++r) {
        const int i = (r == 0) ? rowA : rowB;
        const float4 xi = x4[i];
        const float* __restrict__ erow = eps + (size_t)i * N;
        const float* __restrict__ rrow = rmin + (size_t)i * N;

        int j = i + 1 + (int)threadIdx.x;
        // 4x unrolled body: 4 independent pairs, 12 loads issued back-to-back
        for (; j + 768 < N; j += 1024) {
            const float4 xj0 = x4[j];
            const float4 xj1 = x4[j + 256];
            const float4 xj2 = x4[j + 512];
            const float4 xj3 = x4[j + 768];
            const float e0 = erow[j],       e1 = erow[j + 256];
            const float e2 = erow[j + 512], e3 = erow[j + 768];
            const float m0 = rrow[j],       m1 = rrow[j + 256];
            const float m2 = rrow[j + 512], m3 = rrow[j + 768];
            float a0 = lj_pair(xi, xj0, e0, m0);
            float a1 = lj_pair(xi, xj1, e1, m1);
            float a2 = lj_pair(xi, xj2, e2, m2);
            float a3 = lj_pair(xi, xj3, e3, m3);
            acc += (a0 + a1) + (a2 + a3);
        }
        // tail
        for (; j < N; j += 256) {
            acc += lj_pair(xi, x4[j], erow[j], rrow[j]);
        }
    }
    block_reduce_atomic(acc, out);
}

extern "C" void kernel_launch(void* const* d_in, const int* in_sizes, int n_in,
                              void* d_out, int out_size, void* d_ws, size_t ws_size,
                              hipStream_t stream) {
    const float* x     = (const float*)d_in[0];
    const int*   pairs = (const int*)d_in[1];
    const float* kb    = (const float*)d_in[2];
    const float* b0    = (const float*)d_in[3];
    const float* eps   = (const float*)d_in[4];
    const float* rmin  = (const float*)d_in[5];
    float* out = (float*)d_out;
    float4* x4 = (float4*)d_ws;   // needs NA*16 = 128 KB of workspace

    hipMemsetAsync(out, 0, sizeof(float), stream);
    pack_x_kernel<<<(NA + 255) / 256, 256, 0, stream>>>(x, x4, NA);
    bond_kernel<<<(NB + 255) / 256, 256, 0, stream>>>(x, pairs, kb, b0, out);
    lj_kernel<<<NA / 2, 256, 0, stream>>>(x4, eps, rmin, out);
}